// Round 13
// baseline (436.849 us; speedup 1.0000x reference)
//
#include <hip/hip_runtime.h>
#include <hip/hip_bf16.h>
#include <stdint.h>

#define SEQ    2048
#define HIDDEN 1024
#define NH     16
#define HD     64

// log2(e)/8 : folds both the 1/sqrt(64) scale and the exp->exp2 conversion
#define SC_LOG2E_8 0.18033688011112042f
// static softmax shift (log2 domain): exp2(score - 16), normalized by l at the end
#define SM_SHIFT   16.0f

typedef __bf16 bf16x8 __attribute__((ext_vector_type(8)));
typedef float  f32x4  __attribute__((ext_vector_type(4)));
typedef float  f32x16 __attribute__((ext_vector_type(16)));
typedef unsigned int uint32x2 __attribute__((ext_vector_type(2)));

typedef __attribute__((address_space(1))) void* as1vp;
typedef __attribute__((address_space(3))) void* as3vp;

__device__ __forceinline__ void gload_lds16(const void* g, void* l) {
  __builtin_amdgcn_global_load_lds((as1vp)(void*)g, (as3vp)l, 16, 0, 0);
}

__device__ __forceinline__ uint16_t f2bf(float f) {
  uint32_t x;
  __builtin_memcpy(&x, &f, 4);
  x += 0x7FFFu + ((x >> 16) & 1u);   // round-to-nearest-even
  return (uint16_t)(x >> 16);
}

// pack two floats to one u32 of 2 bf16 (lo, hi)
__device__ __forceinline__ uint32_t pkbf(float lo, float hi) {
  union { __bf16 v[2]; uint32_t u; } t;
  t.v[0] = (__bf16)lo; t.v[1] = (__bf16)hi;
  return t.u;
}

// v_permlane32_swap_b32 (builtin): swaps vdst[32:63] <-> vsrc[0:31].
__device__ __forceinline__ uint32x2 plswap(uint32_t lo, uint32_t hi) {
  return __builtin_amdgcn_permlane32_swap(lo, hi, false, false);
}

// value held by partner lane (lane ^ 32)
__device__ __forceinline__ float xhalf32(float x, int lane) {
  uint32_t a;
  __builtin_memcpy(&a, &x, 4);
  uint32x2 r = plswap(a, a);
  uint32_t p = (lane < 32) ? r[1] : r[0];
  float f;
  __builtin_memcpy(&f, &p, 4);
  return f;
}

__device__ __forceinline__ float exp2_fast(float x) {
  return __builtin_amdgcn_exp2f(x);
}

// ---------------------------------------------------------------------------
// Convert Q/K/V fp32 -> bf16 (tensor by blockIdx.y); blocks x==2048 (y<2)
// produce mask_sc = mask * log2e/8 - SM_SHIFT (used as QK^T C-init).
// ---------------------------------------------------------------------------
__global__ __launch_bounds__(256) void k_cvt(
    const float* __restrict__ Q, const float* __restrict__ K, const float* __restrict__ V,
    const float* __restrict__ mask,
    uint16_t* __restrict__ Qb, uint16_t* __restrict__ Kb, uint16_t* __restrict__ Vb,
    float* __restrict__ mask_sc) {
  if (blockIdx.x == 2048) {
    if (blockIdx.y < 2) {
      const int i = (blockIdx.y * 256 + threadIdx.x) * 8;   // 2 blocks x 2048 = 4096
      float4 a = *(const float4*)(mask + i);
      float4 b = *(const float4*)(mask + i + 4);
      a.x = a.x * SC_LOG2E_8 - SM_SHIFT; a.y = a.y * SC_LOG2E_8 - SM_SHIFT;
      a.z = a.z * SC_LOG2E_8 - SM_SHIFT; a.w = a.w * SC_LOG2E_8 - SM_SHIFT;
      b.x = b.x * SC_LOG2E_8 - SM_SHIFT; b.y = b.y * SC_LOG2E_8 - SM_SHIFT;
      b.z = b.z * SC_LOG2E_8 - SM_SHIFT; b.w = b.w * SC_LOG2E_8 - SM_SHIFT;
      *(float4*)(mask_sc + i) = a;
      *(float4*)(mask_sc + i + 4) = b;
    }
    return;
  }
  const float* src = (blockIdx.y == 0) ? Q : (blockIdx.y == 1) ? K : V;
  uint16_t*    dst = (blockIdx.y == 0) ? Qb : (blockIdx.y == 1) ? Kb : Vb;
  const int i = (blockIdx.x * 256 + threadIdx.x) * 8;
  float4 v0 = *(const float4*)(src + i);
  float4 v1 = *(const float4*)(src + i + 4);
  uint16_t tmp[8];
  tmp[0] = f2bf(v0.x); tmp[1] = f2bf(v0.y); tmp[2] = f2bf(v0.z); tmp[3] = f2bf(v0.w);
  tmp[4] = f2bf(v1.x); tmp[5] = f2bf(v1.y); tmp[6] = f2bf(v1.z); tmp[7] = f2bf(v1.w);
  __builtin_memcpy(dst + i, tmp, 16);
}

// ---------------------------------------------------------------------------
// Transpose W fp32 [K=1024][N=1024] -> WT bf16 [N][K] (matrix by blockIdx.y)
// ---------------------------------------------------------------------------
__global__ __launch_bounds__(256) void k_transpose(
    const float* __restrict__ W0, const float* __restrict__ W1, const float* __restrict__ W2,
    uint16_t* __restrict__ T0, uint16_t* __restrict__ T1, uint16_t* __restrict__ T2) {
  __shared__ uint16_t t[64][65];
  const float* W = (blockIdx.y == 0) ? W0 : (blockIdx.y == 1) ? W1 : W2;
  uint16_t*    T = (blockIdx.y == 0) ? T0 : (blockIdx.y == 1) ? T1 : T2;
  const int bx = blockIdx.x & 15, by = blockIdx.x >> 4;
  const int tx = threadIdx.x & 63, ty = threadIdx.x >> 6;
  for (int i = ty; i < 64; i += 4)
    t[i][tx] = f2bf(W[(by * 64 + i) * HIDDEN + bx * 64 + tx]);
  __syncthreads();
  for (int i = ty; i < 64; i += 4)
    T[(bx * 64 + i) * HIDDEN + by * 64 + tx] = t[tx][i];
}

// ---------------------------------------------------------------------------
// QKV projection GEMM (unchanged from round 12): bf16 in / bf16 out, B^T via
// WT. 128x128 tile, BK=64, 4 waves each 64x64, mfma_16x16x32_bf16. Linear
// bf16 LDS. 1-D grid 768, bijective XCD swizzle. Fragment-major epilogue:
//  q: [bh][qt32(64)][slot(4)][lane(64)][j(8)]  (scaled by log2e/8)
//  k: [bh][kt(32)][c(2)][slot(4)][lane(64)][j(8)]
//  v: [bh][kt(32)][dt(2)][ks(4)][lane(64)][jj(8)]
// ---------------------------------------------------------------------------
__global__ __launch_bounds__(256) void k_qkv_gemm(
    const uint16_t* __restrict__ Qb, const uint16_t* __restrict__ Kb, const uint16_t* __restrict__ Vb,
    const uint16_t* __restrict__ WTq, const uint16_t* __restrict__ WTk, const uint16_t* __restrict__ WTv,
    const float* __restrict__ Bq, const float* __restrict__ Bk, const float* __restrict__ Bv,
    uint16_t* __restrict__ q_ws, uint16_t* __restrict__ k_ws, uint16_t* __restrict__ v_ws) {
  const int wg  = blockIdx.x;
  const int swz = (wg & 7) * 96 + (wg >> 3);
  const int mode = swz >> 8;
  const int rem  = swz & 255;
  const int m0   = (rem >> 3) * 128;
  const int n0   = (rem & 7) * 128;

  const uint16_t* X   = (mode == 0) ? Qb : (mode == 1) ? Kb : Vb;
  const uint16_t* WT  = (mode == 0) ? WTq : (mode == 1) ? WTk : WTv;
  const float*    bia = (mode == 0) ? Bq  : (mode == 1) ? Bk  : Bv;

  __shared__ uint16_t As[128 * 64];
  __shared__ uint16_t Bs[128 * 64];
  char* AsB = (char*)As;
  char* BsB = (char*)Bs;

  const int tid  = threadIdx.x;
  const int lane = tid & 63;
  const int w    = tid >> 6;
  const int wr   = w >> 1, wc = w & 1;

  const int lrow = lane >> 3;
  const int lcol = (lane & 7) * 16;

  f32x4 acc[4][4];
  const f32x4 zero = {0.f, 0.f, 0.f, 0.f};
#pragma unroll
  for (int i = 0; i < 4; ++i)
#pragma unroll
    for (int j = 0; j < 4; ++j) acc[i][j] = zero;

  const char* Ab = (const char*)X;
  const char* Bb = (const char*)WT;

  for (int kt = 0; kt < 16; ++kt) {
    __syncthreads();
    const int kbyte = kt * 128;
#pragma unroll
    for (int i = 0; i < 4; ++i) {
      const int r = w * 32 + i * 8;
      gload_lds16(Ab + (size_t)(m0 + r + lrow) * (HIDDEN * 2) + kbyte + lcol, AsB + r * 128);
      gload_lds16(Bb + (size_t)(n0 + r + lrow) * (HIDDEN * 2) + kbyte + lcol, BsB + r * 128);
    }
    __syncthreads();
#pragma unroll
    for (int kc = 0; kc < 2; ++kc) {
      const int chunk = kc * 64 + (lane >> 4) * 16;
      bf16x8 a[4], b[4];
#pragma unroll
      for (int f = 0; f < 4; ++f) {
        const int ra = wr * 64 + f * 16 + (lane & 15);
        a[f] = *(const bf16x8*)(AsB + ra * 128 + chunk);
        const int rb = wc * 64 + f * 16 + (lane & 15);
        b[f] = *(const bf16x8*)(BsB + rb * 128 + chunk);
      }
#pragma unroll
      for (int fm = 0; fm < 4; ++fm)
#pragma unroll
        for (int fn = 0; fn < 4; ++fn)
          acc[fm][fn] = __builtin_amdgcn_mfma_f32_16x16x32_bf16(a[fm], b[fn], acc[fm][fn], 0, 0, 0);
    }
  }

  float bfrag[4];
#pragma unroll
  for (int fn = 0; fn < 4; ++fn)
    bfrag[fn] = bia[n0 + wc * 64 + fn * 16 + (lane & 15)];

#pragma unroll
  for (int fm = 0; fm < 4; ++fm) {
    const int mrow0 = m0 + wr * 64 + fm * 16 + (lane >> 4) * 4;   // run of 4 rows
    const int b0 = mrow0 >> 11;
    const int sq = mrow0 & (SEQ - 1);
#pragma unroll
    for (int fn = 0; fn < 4; ++fn) {
      const int n = n0 + wc * 64 + fn * 16 + (lane & 15);
      const int h = n >> 6, d = n & 63;
      const size_t bh = (size_t)(b0 * NH + h);
      if (mode == 2) {
        const int kt2 = sq >> 6, ks = (sq >> 4) & 3, hv = (sq >> 3) & 1, jj = sq & 7;
        const int dt = d >> 5, lnv = hv * 32 + (d & 31);
        uint16_t tmp[4];
#pragma unroll
        for (int j = 0; j < 4; ++j) tmp[j] = f2bf(acc[fm][fn][j] + bfrag[fn]);
        __builtin_memcpy(v_ws + ((((bh * 32 + kt2) * 2 + dt) * 4 + ks) * 64 + lnv) * 8 + jj,
                         tmp, 8);
      } else if (mode == 1) {
        const int kt2 = sq >> 6, c = (sq >> 5) & 1, ql = sq & 31;
        const int slot = d >> 4, hk = (d >> 3) & 1, jk = d & 7;
        uint16_t* base = k_ws + ((((bh * 32 + kt2) * 2 + c) * 4 + slot) * 64 + hk * 32 + ql) * 8 + jk;
#pragma unroll
        for (int j = 0; j < 4; ++j) base[j * 8] = f2bf(acc[fm][fn][j] + bfrag[fn]);
      } else {
        const int qt32 = sq >> 5, ql = sq & 31;
        const int slot = d >> 4, hq = (d >> 3) & 1, jq = d & 7;
        uint16_t* base = q_ws + (((bh * 64 + qt32) * 4 + slot) * 64 + hq * 32 + ql) * 8 + jq;
#pragma unroll
        for (int j = 0; j < 4; ++j)
          base[j * 8] = f2bf((acc[fm][fn][j] + bfrag[fn]) * SC_LOG2E_8);
      }
    }
  }
}

// ---------------------------------------------------------------------------
// Flash attention: swapped-QK^T 32x32, fragment-major, static-max softmax.
// TRAFFIC-HALVED: each wave owns 64 q (two 32-q subtiles a,b) and reads K/V
// ONCE per tile for both. Block = (bh, 128 q): wave = (qpair p, KV-half kvh).
// Grid 512, 2048 waves. kvh halves merged per qpair via LDS (plain adds).
// ---------------------------------------------------------------------------
__global__ void k_attn(
    const uint16_t* __restrict__ q_ws, const uint16_t* __restrict__ k_ws,
    const uint16_t* __restrict__ v_ws, const float* __restrict__ mask_sc,
    float* __restrict__ out) {
  __shared__ float smem[2][64][66];   // [qpair][lane][Oa(32) la Ob(32) lb]

  const int tid = threadIdx.x, lane = tid & 63, w = tid >> 6;
  // XCD swizzle: 512 blocks, 8 XCDs, 64 consecutive work-ids per XCD -> 4 bh/XCD
  const int wg  = blockIdx.x;
  const int swz = (wg & 7) * 64 + (wg >> 3);
  const int bh  = swz >> 4;
  const int qt  = swz & 15;           // 128-q tile index
  const int b   = bh >> 4;
  const int h   = bh & 15;
  const int p   = w & 1;              // q-pair within the 128-q tile
  const int kvh = w >> 1;             // KV half
  const int q0  = qt * 128 + p * 64;  // first q of subtile a; b = +32
  const int ql  = lane & 31;
  const int hi  = lane >> 5;

  const char* qfa = (const char*)q_ws + ((size_t)bh * 64 + (q0 >> 5)) * 4096;
  const char* kfb = (const char*)k_ws + (size_t)bh * 262144 + lane * 16;
  const char* vfb = (const char*)v_ws + (size_t)bh * 262144 + lane * 16;
  const float* mrow = mask_sc + b * SEQ;

  // Q B-fragments for both subtiles (coalesced)
  bf16x8 qBa[4], qBb[4];
#pragma unroll
  for (int s = 0; s < 4; ++s) {
    qBa[s] = *(const bf16x8*)(qfa + s * 1024 + lane * 16);
    qBb[s] = *(const bf16x8*)(qfa + 4096 + s * 1024 + lane * 16);
  }

  const f32x16 zero16 = {0.f};
  f32x16 Oa0 = zero16, Oa1 = zero16, Ob0 = zero16, Ob1 = zero16;
  float la = 0.f, lb = 0.f;

  const int kbeg = kvh * 16, kend = kbeg + 16;

  for (int kt = kbeg; kt < kend; ++kt) {
    const char* kt_k = kfb + (size_t)kt * 8192;
    const char* kt_v = vfb + (size_t)kt * 8192;

    // ---- C-init = mask*SC - 16 (key-dependent only: shared by a and b) ----
    f32x16 Pa0, Pa1, Pb0, Pb1;
#pragma unroll
    for (int g = 0; g < 4; ++g) {
      f32x4 mk0 = *(const f32x4*)(mrow + kt * 64 + g * 8 + 4 * hi);
      f32x4 mk1 = *(const f32x4*)(mrow + kt * 64 + 32 + g * 8 + 4 * hi);
#pragma unroll
      for (int t = 0; t < 4; ++t) {
        Pa0[g * 4 + t] = mk0[t]; Pa1[g * 4 + t] = mk1[t];
        Pb0[g * 4 + t] = mk0[t]; Pb1[g * 4 + t] = mk1[t];
      }
    }

    // ---- QK^T for both subtiles, K loaded in 4-fragment chunks ----
    {
      bf16x8 kf[4];
#pragma unroll
      for (int i = 0; i < 4; ++i) kf[i] = *(const bf16x8*)(kt_k + i * 1024);
#pragma unroll
      for (int s = 0; s < 4; ++s)
        Pa0 = __builtin_amdgcn_mfma_f32_32x32x16_bf16(kf[s], qBa[s], Pa0, 0, 0, 0);
#pragma unroll
      for (int s = 0; s < 4; ++s)
        Pb0 = __builtin_amdgcn_mfma_f32_32x32x16_bf16(kf[s], qBb[s], Pb0, 0, 0, 0);
#pragma unroll
      for (int i = 0; i < 4; ++i) kf[i] = *(const bf16x8*)(kt_k + 4096 + i * 1024);
#pragma unroll
      for (int s = 0; s < 4; ++s)
        Pa1 = __builtin_amdgcn_mfma_f32_32x32x16_bf16(kf[s], qBa[s], Pa1, 0, 0, 0);
#pragma unroll
      for (int s = 0; s < 4; ++s)
        Pb1 = __builtin_amdgcn_mfma_f32_32x32x16_bf16(kf[s], qBb[s], Pb1, 0, 0, 0);
    }

    // ---- exp2 + row-sum + pack, subtile a ----
    bf16x8 pba[4], pbb[4];
    {
      float s0 = 0.f, s1 = 0.f, s2 = 0.f, s3 = 0.f;
#pragma unroll
      for (int r = 0; r < 16; r += 4) {
        Pa0[r]     = exp2_fast(Pa0[r]);      s0 += Pa0[r];
        Pa0[r + 1] = exp2_fast(Pa0[r + 1]);  s1 += Pa0[r + 1];
        Pa0[r + 2] = exp2_fast(Pa0[r + 2]);  s2 += Pa0[r + 2];
        Pa0[r + 3] = exp2_fast(Pa0[r + 3]);  s3 += Pa0[r + 3];
        Pa1[r]     = exp2_fast(Pa1[r]);      s0 += Pa1[r];
        Pa1[r + 1] = exp2_fast(Pa1[r + 1]);  s1 += Pa1[r + 1];
        Pa1[r + 2] = exp2_fast(Pa1[r + 2]);  s2 += Pa1[r + 2];
        Pa1[r + 3] = exp2_fast(Pa1[r + 3]);  s3 += Pa1[r + 3];
      }
      la += (s0 + s1) + (s2 + s3);
#pragma unroll
      for (int ks = 0; ks < 4; ++ks) {
        const int o = (ks & 1) * 8;
        uint32_t w0, w1, w2, w3;
        if (ks < 2) {
          w0 = pkbf(Pa0[o + 0], Pa0[o + 1]); w1 = pkbf(Pa0[o + 2], Pa0[o + 3]);
          w2 = pkbf(Pa0[o + 4], Pa0[o + 5]); w3 = pkbf(Pa0[o + 6], Pa0[o + 7]);
        } else {
          w0 = pkbf(Pa1[o + 0], Pa1[o + 1]); w1 = pkbf(Pa1[o + 2], Pa1[o + 3]);
          w2 = pkbf(Pa1[o + 4], Pa1[o + 5]); w3 = pkbf(Pa1[o + 6], Pa1[o + 7]);
        }
        uint32x2 r02 = plswap(w0, w2);
        uint32x2 r13 = plswap(w1, w3);
        uint32_t wv[4] = {r02[0], r13[0], r02[1], r13[1]};
        __builtin_memcpy(&pba[ks], wv, 16);
      }
    }

    // ---- V fragments (shared by both subtiles) ----
    bf16x8 vA[8];
#pragma unroll
    for (int i = 0; i < 8; ++i) vA[i] = *(const bf16x8*)(kt_v + i * 1024);

    // ---- exp2 + row-sum + pack, subtile b (independent of PV(a)) ----
    {
      float s0 = 0.f, s1 = 0.f, s2 = 0.f, s3 = 0.f;
#pragma unroll
      for (int r = 0; r < 16; r += 4) {
        Pb0[r]     = exp2_fast(Pb0[r]);      s0 += Pb0[r];
        Pb0[r + 1] = exp2_fast(Pb0[r + 1]);  s1 += Pb0[r + 1];
        Pb0[r + 2] = exp2_fast(Pb0[r + 2]);  s2 += Pb0[r + 2];
        Pb0[r + 3] = exp2_fast(Pb0[r + 3]);  s3 += Pb0[r + 3];
        Pb1[r]     = exp2_fast(Pb1[r]);      s0 += Pb1[r];
        Pb1[r + 1] = exp2_fast(Pb1[r + 1]);  s1 += Pb1[r + 1];
        Pb1[r + 2] = exp2_fast(Pb1[r + 2]);  s2 += Pb1[r + 2];
        Pb1[r + 3] = exp2_fast(Pb1[r + 3]);  s3 += Pb1[r + 3];
      }
      lb += (s0 + s1) + (s2 + s3);
#pragma unroll
      for (int ks = 0; ks < 4; ++ks) {
        const int o = (ks & 1) * 8;
        uint32_t w0, w1, w2, w3;
        if (ks < 2) {
          w0 = pkbf(Pb0[o + 0], Pb0[o + 1]); w1 = pkbf(Pb0[o + 2], Pb0[o + 3]);
          w2 = pkbf(Pb0[o + 4], Pb0[o + 5]); w3 = pkbf(Pb0[o + 6], Pb0[o + 7]);
        } else {
          w0 = pkbf(Pb1[o + 0], Pb1[o + 1]); w1 = pkbf(Pb1[o + 2], Pb1[o + 3]);
          w2 = pkbf(Pb1[o + 4], Pb1[o + 5]); w3 = pkbf(Pb1[o + 6], Pb1[o + 7]);
        }
        uint32x2 r02 = plswap(w0, w2);
        uint32x2 r13 = plswap(w1, w3);
        uint32_t wv[4] = {r02[0], r13[0], r02[1], r13[1]};
        __builtin_memcpy(&pbb[ks], wv, 16);
      }
    }

    // ---- PV for both subtiles on the same V fragments ----
#pragma unroll
    for (int ks = 0; ks < 4; ++ks) {
      Oa0 = __builtin_amdgcn_mfma_f32_32x32x16_bf16(vA[ks],     pba[ks], Oa0, 0, 0, 0);
      Oa1 = __builtin_amdgcn_mfma_f32_32x32x16_bf16(vA[4 + ks], pba[ks], Oa1, 0, 0, 0);
    }
#pragma unroll
    for (int ks = 0; ks < 4; ++ks) {
      Ob0 = __builtin_amdgcn_mfma_f32_32x32x16_bf16(vA[ks],     pbb[ks], Ob0, 0, 0, 0);
      Ob1 = __builtin_amdgcn_mfma_f32_32x32x16_bf16(vA[4 + ks], pbb[ks], Ob1, 0, 0, 0);
    }
  }

  // ---- merge the two KV halves per qpair (plain adds, shared static shift) ----
  if (kvh == 1) {
    float* s = smem[p][lane];
#pragma unroll
    for (int r = 0; r < 16; ++r) {
      s[r] = Oa0[r]; s[16 + r] = Oa1[r];
      s[33 + r] = Ob0[r]; s[49 + r] = Ob1[r];
    }
    s[32] = la; s[65] = lb;
  }
  __syncthreads();
  if (kvh == 1) return;

  const float* s = smem[p][lane];
#pragma unroll
  for (int r = 0; r < 16; ++r) {
    Oa0[r] += s[r]; Oa1[r] += s[16 + r];
    Ob0[r] += s[33 + r]; Ob1[r] += s[49 + r];
  }
  la += s[32]; lb += s[65];

  const float lat = la + xhalf32(la, lane);
  const float lbt = lb + xhalf32(lb, lane);
  const float lia = 1.f / lat;
  const float lib = 1.f / lbt;

  float* orowa = out + ((size_t)(b * SEQ) + q0 + ql) * HIDDEN + h * HD;
  float* orowb = out + ((size_t)(b * SEQ) + q0 + 32 + ql) * HIDDEN + h * HD;
#pragma unroll
  for (int g = 0; g < 4; ++g) {
    f32x4 o;
#pragma unroll
    for (int t = 0; t < 4; ++t) o[t] = Oa0[g * 4 + t] * lia;
    *(f32x4*)(orowa + g * 8 + 4 * hi) = o;
#pragma unroll
    for (int t = 0; t < 4; ++t) o[t] = Oa1[g * 4 + t] * lia;
    *(f32x4*)(orowa + 32 + g * 8 + 4 * hi) = o;
#pragma unroll
    for (int t = 0; t < 4; ++t) o[t] = Ob0[g * 4 + t] * lib;
    *(f32x4*)(orowb + g * 8 + 4 * hi) = o;
#pragma unroll
    for (int t = 0; t < 4; ++t) o[t] = Ob1[g * 4 + t] * lib;
    *(f32x4*)(orowb + 32 + g * 8 + 4 * hi) = o;
  }
}

// ---------------------------------------------------------------------------
extern "C" void kernel_launch(void* const* d_in, const int* in_sizes, int n_in,
                              void* d_out, int out_size, void* d_ws, size_t ws_size,
                              hipStream_t stream) {
  (void)in_sizes; (void)n_in; (void)out_size; (void)ws_size;
  const float* Q    = (const float*)d_in[0];
  const float* K    = (const float*)d_in[1];
  const float* V    = (const float*)d_in[2];
  const float* mask = (const float*)d_in[3];
  const float* Wq   = (const float*)d_in[4];
  const float* bq   = (const float*)d_in[5];
  const float* Wk   = (const float*)d_in[6];
  const float* bk   = (const float*)d_in[7];
  const float* Wv   = (const float*)d_in[8];
  const float* bv   = (const float*)d_in[9];

  uint16_t* ws   = (uint16_t*)d_ws;
  uint16_t* wt_q = ws;
  uint16_t* wt_k = wt_q + HIDDEN * HIDDEN;
  uint16_t* wt_v = wt_k + HIDDEN * HIDDEN;
  const size_t qkv = (size_t)2 * SEQ * HIDDEN;
  uint16_t* Qb   = wt_v + HIDDEN * HIDDEN;
  uint16_t* Kb   = Qb + qkv;
  uint16_t* Vb   = Kb + qkv;
  uint16_t* q_ws = Vb + qkv;
  uint16_t* k_ws = q_ws + qkv;
  uint16_t* v_ws = k_ws + qkv;
  float* mask_sc = (float*)(v_ws + qkv);       // 4096 floats (16 KB)

  k_cvt<<<dim3(2049, 3), 256, 0, stream>>>(Q, K, V, mask, Qb, Kb, Vb, mask_sc);
  k_transpose<<<dim3(256, 3), 256, 0, stream>>>(Wq, Wk, Wv, wt_q, wt_k, wt_v);
  k_qkv_gemm<<<dim3(768), 256, 0, stream>>>(
      Qb, Kb, Vb, wt_q, wt_k, wt_v, bq, bk, bv, q_ws, k_ws, v_ws);
  k_attn<<<dim3(512), 256, 0, stream>>>(q_ws, k_ws, v_ws, mask_sc,
                                        (float*)d_out);
}

// Round 14
// 131.125 us; speedup vs baseline: 3.3315x; 3.3315x over previous
//
#include <hip/hip_runtime.h>
#include <hip/hip_bf16.h>
#include <stdint.h>

#define SEQ    2048
#define HIDDEN 1024
#define NH     16
#define HD     64

// log2(e)/8 : folds both the 1/sqrt(64) scale and the exp->exp2 conversion
#define SC_LOG2E_8 0.18033688011112042f
// static softmax shift (log2 domain): exp2(score - 16), normalized by l at the end
#define SM_SHIFT   16.0f

typedef __bf16 bf16x8 __attribute__((ext_vector_type(8)));
typedef float  f32x4  __attribute__((ext_vector_type(4)));
typedef float  f32x16 __attribute__((ext_vector_type(16)));
typedef unsigned int uint32x2 __attribute__((ext_vector_type(2)));

typedef __attribute__((address_space(1))) void* as1vp;
typedef __attribute__((address_space(3))) void* as3vp;

__device__ __forceinline__ void gload_lds16(const void* g, void* l) {
  __builtin_amdgcn_global_load_lds((as1vp)(void*)g, (as3vp)l, 16, 0, 0);
}

__device__ __forceinline__ uint16_t f2bf(float f) {
  uint32_t x;
  __builtin_memcpy(&x, &f, 4);
  x += 0x7FFFu + ((x >> 16) & 1u);   // round-to-nearest-even
  return (uint16_t)(x >> 16);
}

// pack two floats to one u32 of 2 bf16 (lo, hi)
__device__ __forceinline__ uint32_t pkbf(float lo, float hi) {
  union { __bf16 v[2]; uint32_t u; } t;
  t.v[0] = (__bf16)lo; t.v[1] = (__bf16)hi;
  return t.u;
}

// v_permlane32_swap_b32 (builtin): swaps vdst[32:63] <-> vsrc[0:31].
__device__ __forceinline__ uint32x2 plswap(uint32_t lo, uint32_t hi) {
  return __builtin_amdgcn_permlane32_swap(lo, hi, false, false);
}

// value held by partner lane (lane ^ 32)
__device__ __forceinline__ float xhalf32(float x, int lane) {
  uint32_t a;
  __builtin_memcpy(&a, &x, 4);
  uint32x2 r = plswap(a, a);
  uint32_t p = (lane < 32) ? r[1] : r[0];
  float f;
  __builtin_memcpy(&f, &p, 4);
  return f;
}

__device__ __forceinline__ float exp2_fast(float x) {
  return __builtin_amdgcn_exp2f(x);
}

// ---------------------------------------------------------------------------
// Convert Q/K/V fp32 -> bf16 (tensor by blockIdx.y); blocks x==2048 (y<2)
// produce mask_sc = mask * log2e/8 - SM_SHIFT (used as QK^T C-init).
// ---------------------------------------------------------------------------
__global__ __launch_bounds__(256) void k_cvt(
    const float* __restrict__ Q, const float* __restrict__ K, const float* __restrict__ V,
    const float* __restrict__ mask,
    uint16_t* __restrict__ Qb, uint16_t* __restrict__ Kb, uint16_t* __restrict__ Vb,
    float* __restrict__ mask_sc) {
  if (blockIdx.x == 2048) {
    if (blockIdx.y < 2) {
      const int i = (blockIdx.y * 256 + threadIdx.x) * 8;   // 2 blocks x 2048 = 4096
      float4 a = *(const float4*)(mask + i);
      float4 b = *(const float4*)(mask + i + 4);
      a.x = a.x * SC_LOG2E_8 - SM_SHIFT; a.y = a.y * SC_LOG2E_8 - SM_SHIFT;
      a.z = a.z * SC_LOG2E_8 - SM_SHIFT; a.w = a.w * SC_LOG2E_8 - SM_SHIFT;
      b.x = b.x * SC_LOG2E_8 - SM_SHIFT; b.y = b.y * SC_LOG2E_8 - SM_SHIFT;
      b.z = b.z * SC_LOG2E_8 - SM_SHIFT; b.w = b.w * SC_LOG2E_8 - SM_SHIFT;
      *(float4*)(mask_sc + i) = a;
      *(float4*)(mask_sc + i + 4) = b;
    }
    return;
  }
  const float* src = (blockIdx.y == 0) ? Q : (blockIdx.y == 1) ? K : V;
  uint16_t*    dst = (blockIdx.y == 0) ? Qb : (blockIdx.y == 1) ? Kb : Vb;
  const int i = (blockIdx.x * 256 + threadIdx.x) * 8;
  float4 v0 = *(const float4*)(src + i);
  float4 v1 = *(const float4*)(src + i + 4);
  uint16_t tmp[8];
  tmp[0] = f2bf(v0.x); tmp[1] = f2bf(v0.y); tmp[2] = f2bf(v0.z); tmp[3] = f2bf(v0.w);
  tmp[4] = f2bf(v1.x); tmp[5] = f2bf(v1.y); tmp[6] = f2bf(v1.z); tmp[7] = f2bf(v1.w);
  __builtin_memcpy(dst + i, tmp, 16);
}

// ---------------------------------------------------------------------------
// Transpose W fp32 [K=1024][N=1024] -> WT bf16 [N][K] (matrix by blockIdx.y)
// ---------------------------------------------------------------------------
__global__ __launch_bounds__(256) void k_transpose(
    const float* __restrict__ W0, const float* __restrict__ W1, const float* __restrict__ W2,
    uint16_t* __restrict__ T0, uint16_t* __restrict__ T1, uint16_t* __restrict__ T2) {
  __shared__ uint16_t t[64][65];
  const float* W = (blockIdx.y == 0) ? W0 : (blockIdx.y == 1) ? W1 : W2;
  uint16_t*    T = (blockIdx.y == 0) ? T0 : (blockIdx.y == 1) ? T1 : T2;
  const int bx = blockIdx.x & 15, by = blockIdx.x >> 4;
  const int tx = threadIdx.x & 63, ty = threadIdx.x >> 6;
  for (int i = ty; i < 64; i += 4)
    t[i][tx] = f2bf(W[(by * 64 + i) * HIDDEN + bx * 64 + tx]);
  __syncthreads();
  for (int i = ty; i < 64; i += 4)
    T[(bx * 64 + i) * HIDDEN + by * 64 + tx] = t[tx][i];
}

// ---------------------------------------------------------------------------
// QKV projection GEMM (unchanged from round 12): bf16 in / bf16 out, B^T via
// WT. 128x128 tile, BK=64, 4 waves each 64x64, mfma_16x16x32_bf16. Linear
// bf16 LDS. 1-D grid 768, bijective XCD swizzle. Fragment-major epilogue:
//  q: [bh][qt32(64)][slot(4)][lane(64)][j(8)]  (scaled by log2e/8)
//  k: [bh][kt(32)][c(2)][slot(4)][lane(64)][j(8)]
//  v: [bh][kt(32)][dt(2)][ks(4)][lane(64)][jj(8)]
// ---------------------------------------------------------------------------
__global__ __launch_bounds__(256) void k_qkv_gemm(
    const uint16_t* __restrict__ Qb, const uint16_t* __restrict__ Kb, const uint16_t* __restrict__ Vb,
    const uint16_t* __restrict__ WTq, const uint16_t* __restrict__ WTk, const uint16_t* __restrict__ WTv,
    const float* __restrict__ Bq, const float* __restrict__ Bk, const float* __restrict__ Bv,
    uint16_t* __restrict__ q_ws, uint16_t* __restrict__ k_ws, uint16_t* __restrict__ v_ws) {
  const int wg  = blockIdx.x;
  const int swz = (wg & 7) * 96 + (wg >> 3);
  const int mode = swz >> 8;
  const int rem  = swz & 255;
  const int m0   = (rem >> 3) * 128;
  const int n0   = (rem & 7) * 128;

  const uint16_t* X   = (mode == 0) ? Qb : (mode == 1) ? Kb : Vb;
  const uint16_t* WT  = (mode == 0) ? WTq : (mode == 1) ? WTk : WTv;
  const float*    bia = (mode == 0) ? Bq  : (mode == 1) ? Bk  : Bv;

  __shared__ uint16_t As[128 * 64];
  __shared__ uint16_t Bs[128 * 64];
  char* AsB = (char*)As;
  char* BsB = (char*)Bs;

  const int tid  = threadIdx.x;
  const int lane = tid & 63;
  const int w    = tid >> 6;
  const int wr   = w >> 1, wc = w & 1;

  const int lrow = lane >> 3;
  const int lcol = (lane & 7) * 16;

  f32x4 acc[4][4];
  const f32x4 zero = {0.f, 0.f, 0.f, 0.f};
#pragma unroll
  for (int i = 0; i < 4; ++i)
#pragma unroll
    for (int j = 0; j < 4; ++j) acc[i][j] = zero;

  const char* Ab = (const char*)X;
  const char* Bb = (const char*)WT;

  for (int kt = 0; kt < 16; ++kt) {
    __syncthreads();
    const int kbyte = kt * 128;
#pragma unroll
    for (int i = 0; i < 4; ++i) {
      const int r = w * 32 + i * 8;
      gload_lds16(Ab + (size_t)(m0 + r + lrow) * (HIDDEN * 2) + kbyte + lcol, AsB + r * 128);
      gload_lds16(Bb + (size_t)(n0 + r + lrow) * (HIDDEN * 2) + kbyte + lcol, BsB + r * 128);
    }
    __syncthreads();
#pragma unroll
    for (int kc = 0; kc < 2; ++kc) {
      const int chunk = kc * 64 + (lane >> 4) * 16;
      bf16x8 a[4], b[4];
#pragma unroll
      for (int f = 0; f < 4; ++f) {
        const int ra = wr * 64 + f * 16 + (lane & 15);
        a[f] = *(const bf16x8*)(AsB + ra * 128 + chunk);
        const int rb = wc * 64 + f * 16 + (lane & 15);
        b[f] = *(const bf16x8*)(BsB + rb * 128 + chunk);
      }
#pragma unroll
      for (int fm = 0; fm < 4; ++fm)
#pragma unroll
        for (int fn = 0; fn < 4; ++fn)
          acc[fm][fn] = __builtin_amdgcn_mfma_f32_16x16x32_bf16(a[fm], b[fn], acc[fm][fn], 0, 0, 0);
    }
  }

  float bfrag[4];
#pragma unroll
  for (int fn = 0; fn < 4; ++fn)
    bfrag[fn] = bia[n0 + wc * 64 + fn * 16 + (lane & 15)];

#pragma unroll
  for (int fm = 0; fm < 4; ++fm) {
    const int mrow0 = m0 + wr * 64 + fm * 16 + (lane >> 4) * 4;   // run of 4 rows
    const int b0 = mrow0 >> 11;
    const int sq = mrow0 & (SEQ - 1);
#pragma unroll
    for (int fn = 0; fn < 4; ++fn) {
      const int n = n0 + wc * 64 + fn * 16 + (lane & 15);
      const int h = n >> 6, d = n & 63;
      const size_t bh = (size_t)(b0 * NH + h);
      if (mode == 2) {
        const int kt2 = sq >> 6, ks = (sq >> 4) & 3, hv = (sq >> 3) & 1, jj = sq & 7;
        const int dt = d >> 5, lnv = hv * 32 + (d & 31);
        uint16_t tmp[4];
#pragma unroll
        for (int j = 0; j < 4; ++j) tmp[j] = f2bf(acc[fm][fn][j] + bfrag[fn]);
        __builtin_memcpy(v_ws + ((((bh * 32 + kt2) * 2 + dt) * 4 + ks) * 64 + lnv) * 8 + jj,
                         tmp, 8);
      } else if (mode == 1) {
        const int kt2 = sq >> 6, c = (sq >> 5) & 1, ql = sq & 31;
        const int slot = d >> 4, hk = (d >> 3) & 1, jk = d & 7;
        uint16_t* base = k_ws + ((((bh * 32 + kt2) * 2 + c) * 4 + slot) * 64 + hk * 32 + ql) * 8 + jk;
#pragma unroll
        for (int j = 0; j < 4; ++j) base[j * 8] = f2bf(acc[fm][fn][j] + bfrag[fn]);
      } else {
        const int qt32 = sq >> 5, ql = sq & 31;
        const int slot = d >> 4, hq = (d >> 3) & 1, jq = d & 7;
        uint16_t* base = q_ws + (((bh * 64 + qt32) * 4 + slot) * 64 + hq * 32 + ql) * 8 + jq;
#pragma unroll
        for (int j = 0; j < 4; ++j)
          base[j * 8] = f2bf((acc[fm][fn][j] + bfrag[fn]) * SC_LOG2E_8);
      }
    }
  }
}

// ---------------------------------------------------------------------------
// Flash attention: swapped-QK^T 32x32, fragment-major, static-max softmax.
// LDS-SHARED K/V: block = (bh, 128 q), 4 waves each own a 32-q subtile and
// loop ALL 32 kt tiles on a double-buffered 2x16KB LDS K/V tile staged once
// per block via global_load_lds (4x cut in per-CU global->L1 traffic vs
// per-wave register loads -- the round-12 plateau). No split-KV, no merge.
// Grid 512, bijective XCD swizzle.
// ---------------------------------------------------------------------------
__global__ __launch_bounds__(256) void k_attn(
    const uint16_t* __restrict__ q_ws, const uint16_t* __restrict__ k_ws,
    const uint16_t* __restrict__ v_ws, const float* __restrict__ mask_sc,
    float* __restrict__ out) {
  __shared__ char lds[2][16384];      // [buf][K 8KB | V 8KB]

  const int tid = threadIdx.x, lane = tid & 63, w = tid >> 6;
  // XCD swizzle: 512 blocks, 8 XCDs, 64 consecutive work-ids per XCD -> 4 bh/XCD
  const int wg  = blockIdx.x;
  const int swz = (wg & 7) * 64 + (wg >> 3);
  const int bh  = swz >> 4;
  const int qt  = swz & 15;           // 128-q tile index
  const int b   = bh >> 4;
  const int h   = bh & 15;
  const int q0  = qt * 128 + w * 32;  // this wave's 32-q subtile
  const int ql  = lane & 31;
  const int hi  = lane >> 5;

  const char* qfb = (const char*)q_ws + ((size_t)bh * 64 + (q0 >> 5)) * 4096;
  const char* kgb = (const char*)k_ws + (size_t)bh * 262144 + w * 2048 + lane * 16;
  const char* vgb = (const char*)v_ws + (size_t)bh * 262144 + w * 2048 + lane * 16;
  const float* mrow = mask_sc + b * SEQ;

  // Q B-fragments (coalesced)
  bf16x8 qB[4];
#pragma unroll
  for (int s = 0; s < 4; ++s)
    qB[s] = *(const bf16x8*)(qfb + s * 1024 + lane * 16);

  const f32x16 zero16 = {0.f};
  f32x16 Oacc[2];
  Oacc[0] = zero16; Oacc[1] = zero16;
  float lpart = 0.f;

  // stage tile kt into lds[buf]: wave w covers bytes [w*2048, w*2048+2047]
  // of both the K half and the V half (4 x global_load_lds per wave).
  auto stage = [&](int buf, int kt) {
    const char* gk = kgb + (size_t)kt * 8192;
    const char* gv = vgb + (size_t)kt * 8192;
    char* l = &lds[buf][w * 2048];
#pragma unroll
    for (int i = 0; i < 2; ++i) {
      gload_lds16(gk + i * 1024, l + i * 1024);
      gload_lds16(gv + i * 1024, l + 8192 + i * 1024);
    }
  };

  stage(0, 0);
  __syncthreads();                    // compiler drains vmcnt before s_barrier

  int cur = 0;
  for (int kt = 0; kt < 32; ++kt) {
    // ---- issue next tile's staging first (hidden under compute) ----
    if (kt + 1 < 32) stage(cur ^ 1, kt + 1);

    const char* lk = &lds[cur][0];
    const char* lv = &lds[cur][8192];

    // ---- C-init = mask*SC - 16 (per key row) ----
    f32x16 P0, P1;
#pragma unroll
    for (int g = 0; g < 4; ++g) {
      f32x4 mk0 = *(const f32x4*)(mrow + kt * 64 + g * 8 + 4 * hi);
      f32x4 mk1 = *(const f32x4*)(mrow + kt * 64 + 32 + g * 8 + 4 * hi);
#pragma unroll
      for (int t = 0; t < 4; ++t) { P0[g * 4 + t] = mk0[t]; P1[g * 4 + t] = mk1[t]; }
    }

    // ---- K fragments from LDS (contiguous ds_read_b128, conflict-free) ----
    bf16x8 kf[8];
#pragma unroll
    for (int i = 0; i < 8; ++i) kf[i] = *(const bf16x8*)(lk + i * 1024 + lane * 16);

    // ---- QK^T: S^T[key][q] accumulated onto the mask-init ----
#pragma unroll
    for (int s = 0; s < 4; ++s)
      P0 = __builtin_amdgcn_mfma_f32_32x32x16_bf16(kf[s], qB[s], P0, 0, 0, 0);
#pragma unroll
    for (int s = 0; s < 4; ++s)
      P1 = __builtin_amdgcn_mfma_f32_32x32x16_bf16(kf[4 + s], qB[s], P1, 0, 0, 0);

    // ---- V fragments from LDS ----
    bf16x8 vA[8];
#pragma unroll
    for (int i = 0; i < 8; ++i) vA[i] = *(const bf16x8*)(lv + i * 1024 + lane * 16);

    // ---- exp2 (no subtract) + partial row-sum ----
    float s0 = 0.f, s1 = 0.f, s2a = 0.f, s3 = 0.f;
#pragma unroll
    for (int r = 0; r < 16; r += 4) {
      P0[r]     = exp2_fast(P0[r]);      s0  += P0[r];
      P0[r + 1] = exp2_fast(P0[r + 1]);  s1  += P0[r + 1];
      P0[r + 2] = exp2_fast(P0[r + 2]);  s2a += P0[r + 2];
      P0[r + 3] = exp2_fast(P0[r + 3]);  s3  += P0[r + 3];
      P1[r]     = exp2_fast(P1[r]);      s0  += P1[r];
      P1[r + 1] = exp2_fast(P1[r + 1]);  s1  += P1[r + 1];
      P1[r + 2] = exp2_fast(P1[r + 2]);  s2a += P1[r + 2];
      P1[r + 3] = exp2_fast(P1[r + 3]);  s3  += P1[r + 3];
    }
    lpart += (s0 + s1) + (s2a + s3);

    // ---- pack P^T into PV B-fragments: cvt_pk + permlane32_swap ----
    bf16x8 pb[4];
#pragma unroll
    for (int ks = 0; ks < 4; ++ks) {
      const int o = (ks & 1) * 8;
      uint32_t w0, w1, w2, w3;
      if (ks < 2) {
        w0 = pkbf(P0[o + 0], P0[o + 1]);
        w1 = pkbf(P0[o + 2], P0[o + 3]);
        w2 = pkbf(P0[o + 4], P0[o + 5]);
        w3 = pkbf(P0[o + 6], P0[o + 7]);
      } else {
        w0 = pkbf(P1[o + 0], P1[o + 1]);
        w1 = pkbf(P1[o + 2], P1[o + 3]);
        w2 = pkbf(P1[o + 4], P1[o + 5]);
        w3 = pkbf(P1[o + 6], P1[o + 7]);
      }
      uint32x2 r02 = plswap(w0, w2);
      uint32x2 r13 = plswap(w1, w3);
      uint32_t wv[4] = {r02[0], r13[0], r02[1], r13[1]};
      __builtin_memcpy(&pb[ks], wv, 16);
    }

    // ---- PV: O^T[d][q] += V^T[d][k] * P^T[k][q] ----
#pragma unroll
    for (int ks = 0; ks < 4; ++ks) {
      Oacc[0] = __builtin_amdgcn_mfma_f32_32x32x16_bf16(vA[ks],     pb[ks], Oacc[0], 0, 0, 0);
      Oacc[1] = __builtin_amdgcn_mfma_f32_32x32x16_bf16(vA[4 + ks], pb[ks], Oacc[1], 0, 0, 0);
    }

    // ---- tile boundary: staging of buf^1 must land; readers of buf done ----
    __syncthreads();
    cur ^= 1;
  }

  // ---- epilogue: per-wave normalize and write (no merge needed) ----
  const float ltot = lpart + xhalf32(lpart, lane);
  const float linv = 1.f / ltot;
  float* orow = out + ((size_t)(b * SEQ) + q0 + ql) * HIDDEN + h * HD;
#pragma unroll
  for (int dt = 0; dt < 2; ++dt)
#pragma unroll
    for (int g = 0; g < 4; ++g) {
      f32x4 o;
#pragma unroll
      for (int t = 0; t < 4; ++t) o[t] = Oacc[dt][g * 4 + t] * linv;
      *(f32x4*)(orow + dt * 32 + g * 8 + 4 * hi) = o;
    }
}

// ---------------------------------------------------------------------------
extern "C" void kernel_launch(void* const* d_in, const int* in_sizes, int n_in,
                              void* d_out, int out_size, void* d_ws, size_t ws_size,
                              hipStream_t stream) {
  (void)in_sizes; (void)n_in; (void)out_size; (void)ws_size;
  const float* Q    = (const float*)d_in[0];
  const float* K    = (const float*)d_in[1];
  const float* V    = (const float*)d_in[2];
  const float* mask = (const float*)d_in[3];
  const float* Wq   = (const float*)d_in[4];
  const float* bq   = (const float*)d_in[5];
  const float* Wk   = (const float*)d_in[6];
  const float* bk   = (const float*)d_in[7];
  const float* Wv   = (const float*)d_in[8];
  const float* bv   = (const float*)d_in[9];

  uint16_t* ws   = (uint16_t*)d_ws;
  uint16_t* wt_q = ws;
  uint16_t* wt_k = wt_q + HIDDEN * HIDDEN;
  uint16_t* wt_v = wt_k + HIDDEN * HIDDEN;
  const size_t qkv = (size_t)2 * SEQ * HIDDEN;
  uint16_t* Qb   = wt_v + HIDDEN * HIDDEN;
  uint16_t* Kb   = Qb + qkv;
  uint16_t* Vb   = Kb + qkv;
  uint16_t* q_ws = Vb + qkv;
  uint16_t* k_ws = q_ws + qkv;
  uint16_t* v_ws = k_ws + qkv;
  float* mask_sc = (float*)(v_ws + qkv);       // 4096 floats (16 KB)

  k_cvt<<<dim3(2049, 3), 256, 0, stream>>>(Q, K, V, mask, Qb, Kb, Vb, mask_sc);
  k_transpose<<<dim3(256, 3), 256, 0, stream>>>(Wq, Wk, Wv, wt_q, wt_k, wt_v);
  k_qkv_gemm<<<dim3(768), 256, 0, stream>>>(
      Qb, Kb, Vb, wt_q, wt_k, wt_v, bq, bk, bv, q_ws, k_ws, v_ws);
  k_attn<<<dim3(512), 256, 0, stream>>>(q_ws, k_ws, v_ws, mask_sc,
                                        (float*)d_out);
}